// Round 2
// baseline (1161.321 us; speedup 1.0000x reference)
//
#include <hip/hip_runtime.h>
#include <hip/hip_fp16.h>

// MoE B=2,N=2048,C=1024,F=4096,E=8,K=2 (T=4096 tokens)
// router -> lists -> cvt weights fp32->fp16 -> gather GEMM1 (relu) -> gather GEMM2 (+scale, atomicAdd)
// GEMMs: 128x128x64 tiles, mfma_f32_16x16x32_f16, global_load_lds(16B) staging,
// XOR swizzle applied on the GLOBAL source address (LDS dest linear) + same XOR on ds_read.

#define T_TOK 4096
#define C_DIM 1024
#define F_DIM 4096
#define E_NUM 8
#define K_TOP 2
#define BM 128
#define BN 128
#define BK 64

typedef float f32x4 __attribute__((ext_vector_type(4)));
typedef _Float16 half8 __attribute__((ext_vector_type(8)));

#define AS1 __attribute__((address_space(1)))
#define AS3 __attribute__((address_space(3)))

__device__ __forceinline__ int swz(int r, int ec) { return ec ^ ((r & 7) << 3); }

// ---------------- Router: logits -> softmax -> top2 -> weights; also x -> fp16
__global__ __launch_bounds__(256) void router_kernel(
    const float* __restrict__ x, const float* __restrict__ rw,
    int* __restrict__ top_idx, float* __restrict__ top_w, _Float16* __restrict__ xh)
{
  int t = blockIdx.x * 4 + (threadIdx.x >> 6);
  int lane = threadIdx.x & 63;
  const float* xr = x + (size_t)t * C_DIM;
  float acc[E_NUM];
#pragma unroll
  for (int e = 0; e < E_NUM; ++e) acc[e] = 0.f;
  for (int j = 0; j < C_DIM / 64; ++j) {
    int c = j * 64 + lane;
    float xv = xr[c];
    xh[(size_t)t * C_DIM + c] = (_Float16)xv;
#pragma unroll
    for (int e = 0; e < E_NUM; ++e) acc[e] += xv * rw[e * C_DIM + c];
  }
#pragma unroll
  for (int e = 0; e < E_NUM; ++e) {
    float v = acc[e];
#pragma unroll
    for (int off = 32; off > 0; off >>= 1) v += __shfl_xor(v, off);
    acc[e] = v;
  }
  if (lane == 0) {
    float mx = acc[0];
    for (int e = 1; e < E_NUM; ++e) mx = fmaxf(mx, acc[e]);
    float p[E_NUM]; float Z = 0.f;
    for (int e = 0; e < E_NUM; ++e) { p[e] = expf(acc[e] - mx); Z += p[e]; }
    int b0 = 0;
    for (int e = 1; e < E_NUM; ++e) if (p[e] > p[b0]) b0 = e;
    int b1i = -1; float pb = -1.f;
    for (int e = 0; e < E_NUM; ++e) if (e != b0 && p[e] > pb) { pb = p[e]; b1i = e; }
    float p0 = p[b0] / Z, p1 = pb / Z;
    float s = p0 + p1 + 1e-9f;
    top_idx[t * 2 + 0] = b0;
    top_idx[t * 2 + 1] = b1i;
    top_w[t * 2 + 0] = p0 / s;
    top_w[t * 2 + 1] = p1 / s;
  }
}

// ---------------- Per-expert token lists (token order = deterministic)
__global__ void build_lists(const int* __restrict__ top_idx,
                            int* __restrict__ rows, int* __restrict__ counts)
{
  int e = blockIdx.x;
  int lane = threadIdx.x;  // one wave
  int base = 0;
  for (int t0 = 0; t0 < T_TOK; t0 += 64) {
    int t = t0 + lane;
    int i0 = top_idx[t * 2], i1 = top_idx[t * 2 + 1];
    bool sel = (i0 == e) || (i1 == e);
    int slot = (i0 == e) ? 0 : 1;
    unsigned long long mask = __ballot(sel);
    if (sel) {
      int pos = base + __popcll(mask & ((1ull << lane) - 1ull));
      rows[e * T_TOK + pos] = t * 2 + slot;
    }
    base += __popcll(mask);
  }
  if (lane == 0) counts[e] = base;
}

// ---------------- fp32 -> fp16 weight conversion (chunk-packed layouts)
// w1h[e][r][c], r in [fc0, fc0+Fc) of F
__global__ __launch_bounds__(256) void cvt_w1_kernel(
    const float* __restrict__ src, _Float16* __restrict__ dst, int fc0, int Fc)
{
  unsigned g = blockIdx.x * 256 + threadIdx.x;     // one 8-elem chunk each
  unsigned col8 = g & (C_DIM / 8 - 1);
  unsigned row = g >> 7;                           // / (C/8)
  unsigned e = row / (unsigned)Fc, r = row % (unsigned)Fc;
  const float4* s = reinterpret_cast<const float4*>(
      src + ((size_t)e * F_DIM + fc0 + r) * C_DIM + col8 * 8);
  float4 f0 = s[0], f1 = s[1];
  half8 hv;
  hv[0] = (_Float16)f0.x; hv[1] = (_Float16)f0.y; hv[2] = (_Float16)f0.z; hv[3] = (_Float16)f0.w;
  hv[4] = (_Float16)f1.x; hv[5] = (_Float16)f1.y; hv[6] = (_Float16)f1.z; hv[7] = (_Float16)f1.w;
  *reinterpret_cast<half8*>(dst + (size_t)g * 8) = hv;
}

// w2h[e][c][r], r in [fc0, fc0+Fc) of F
__global__ __launch_bounds__(256) void cvt_w2_kernel(
    const float* __restrict__ src, _Float16* __restrict__ dst, int fc0, int Fc)
{
  unsigned g = blockIdx.x * 256 + threadIdx.x;
  unsigned fc8 = (unsigned)Fc / 8;
  unsigned col8 = g % fc8;
  unsigned row = g / fc8;                          // e*C + c
  const float4* s = reinterpret_cast<const float4*>(
      src + (size_t)row * F_DIM + fc0 + col8 * 8);
  float4 f0 = s[0], f1 = s[1];
  half8 hv;
  hv[0] = (_Float16)f0.x; hv[1] = (_Float16)f0.y; hv[2] = (_Float16)f0.z; hv[3] = (_Float16)f0.w;
  hv[4] = (_Float16)f1.x; hv[5] = (_Float16)f1.y; hv[6] = (_Float16)f1.z; hv[7] = (_Float16)f1.w;
  *reinterpret_cast<half8*>(dst + (size_t)g * 8) = hv;
}

// ---------------- GEMM1: h[slot, f] = relu(x[t] . w1h[e][f] + b1), fp16 out
__global__ __launch_bounds__(256) void gemm1_kernel(
    const _Float16* __restrict__ xh, const _Float16* __restrict__ w1h,
    const float* __restrict__ b1, const int* __restrict__ rows_,
    const int* __restrict__ counts, _Float16* __restrict__ hbuf,
    int fc0, int Fc)
{
  const int e = blockIdx.z;
  const int ne = counts[e];
  const int rt = blockIdx.x;
  if (rt * BM >= ne) return;
  const int nrem = min(ne - rt * BM, BM);
  const int ft = blockIdx.y;
  const int* rlist = rows_ + e * T_TOK + rt * BM;
  const _Float16* wB = w1h + ((size_t)e * Fc + (size_t)ft * BN) * C_DIM;

  __shared__ __align__(16) _Float16 As[BM * BK];
  __shared__ __align__(16) _Float16 Bs[BN * BK];

  const int tid = threadIdx.x;
  const int lane = tid & 63;
  const int wave = tid >> 6;
  const int wr = wave >> 1, wc = wave & 1;
  const int cc = lane & 7, r8 = lane >> 3;

  // per-lane global sources; column chunk pre-swizzled (cc ^ r8), LDS dest linear
  const _Float16* aP[4];
  const _Float16* bP[4];
#pragma unroll
  for (int c = 0; c < 4; ++c) {
    int rl = (wave * 4 + c) * 8 + r8;              // 0..127; rl&7 == r8
    int rid = rl < nrem ? rl : nrem - 1;
    int slot = rlist[rid];
    aP[c] = xh + (size_t)(slot >> 1) * C_DIM + (cc ^ r8) * 8;
    bP[c] = wB + (size_t)rl * C_DIM + (cc ^ r8) * 8;
  }

  f32x4 acc[4][4];
#pragma unroll
  for (int m = 0; m < 4; ++m)
#pragma unroll
    for (int n = 0; n < 4; ++n) acc[m][n] = (f32x4){0.f, 0.f, 0.f, 0.f};

  for (int k0 = 0; k0 < C_DIM; k0 += BK) {
#pragma unroll
    for (int c = 0; c < 4; ++c) {
      __builtin_amdgcn_global_load_lds((const AS1 void*)(aP[c] + k0),
                                       (AS3 void*)(As + (wave * 4 + c) * 512), 16, 0, 0);
      __builtin_amdgcn_global_load_lds((const AS1 void*)(bP[c] + k0),
                                       (AS3 void*)(Bs + (wave * 4 + c) * 512), 16, 0, 0);
    }
    __syncthreads();
#pragma unroll
    for (int kk = 0; kk < BK; kk += 32) {
      const int klo = kk + (lane >> 4) * 8;
      half8 aF[4], bF[4];
#pragma unroll
      for (int m = 0; m < 4; ++m) {
        int r = wr * 64 + m * 16 + (lane & 15);
        aF[m] = *reinterpret_cast<const half8*>(&As[r * BK + swz(r, klo)]);
      }
#pragma unroll
      for (int n = 0; n < 4; ++n) {
        int r = wc * 64 + n * 16 + (lane & 15);
        bF[n] = *reinterpret_cast<const half8*>(&Bs[r * BK + swz(r, klo)]);
      }
#pragma unroll
      for (int m = 0; m < 4; ++m)
#pragma unroll
        for (int n = 0; n < 4; ++n)
          acc[m][n] = __builtin_amdgcn_mfma_f32_16x16x32_f16(aF[m], bF[n], acc[m][n], 0, 0, 0);
    }
    __syncthreads();
  }

#pragma unroll
  for (int m = 0; m < 4; ++m) {
#pragma unroll
    for (int j = 0; j < 4; ++j) {
      int iloc = wr * 64 + m * 16 + (lane >> 4) * 4 + j;
      if (iloc < nrem) {
        int slot = rlist[iloc];
#pragma unroll
        for (int n = 0; n < 4; ++n) {
          int fl = ft * BN + wc * 64 + n * 16 + (lane & 15);
          float v = acc[m][n][j] + b1[e * F_DIM + fc0 + fl];
          hbuf[(size_t)slot * Fc + fl] = (_Float16)fmaxf(v, 0.f);
        }
      }
    }
  }
}

// ---------------- GEMM2: out[t] += top_w[slot] * (h[slot] . w2h[e][c] + b2)
__global__ __launch_bounds__(256) void gemm2_kernel(
    const _Float16* __restrict__ hbuf, const _Float16* __restrict__ w2h,
    const float* __restrict__ b2, const int* __restrict__ rows_,
    const int* __restrict__ counts, const float* __restrict__ top_w,
    float* __restrict__ out, int Fc, int kspl, int add_bias)
{
  const int e = blockIdx.z;
  const int ne = counts[e];
  const int rt = blockIdx.x;
  if (rt * BM >= ne) return;
  const int nrem = min(ne - rt * BM, BM);
  const int ct = blockIdx.y & 7;
  const int ks = blockIdx.y >> 3;
  const int klen = Fc / kspl;
  const int kbeg = ks * klen;
  const int* rlist = rows_ + e * T_TOK + rt * BM;
  const _Float16* wB = w2h + ((size_t)e * C_DIM + (size_t)ct * BN) * Fc;

  __shared__ __align__(16) _Float16 As[BM * BK];
  __shared__ __align__(16) _Float16 Bs[BN * BK];

  const int tid = threadIdx.x;
  const int lane = tid & 63;
  const int wave = tid >> 6;
  const int wr = wave >> 1, wc = wave & 1;
  const int cc = lane & 7, r8 = lane >> 3;

  const _Float16* aP[4];
  const _Float16* bP[4];
#pragma unroll
  for (int c = 0; c < 4; ++c) {
    int rl = (wave * 4 + c) * 8 + r8;
    int rid = rl < nrem ? rl : nrem - 1;
    int slot = rlist[rid];
    aP[c] = hbuf + (size_t)slot * Fc + (cc ^ r8) * 8;
    bP[c] = wB + (size_t)rl * Fc + (cc ^ r8) * 8;
  }

  f32x4 acc[4][4];
#pragma unroll
  for (int m = 0; m < 4; ++m)
#pragma unroll
    for (int n = 0; n < 4; ++n) acc[m][n] = (f32x4){0.f, 0.f, 0.f, 0.f};

  for (int k0 = kbeg; k0 < kbeg + klen; k0 += BK) {
#pragma unroll
    for (int c = 0; c < 4; ++c) {
      __builtin_amdgcn_global_load_lds((const AS1 void*)(aP[c] + k0),
                                       (AS3 void*)(As + (wave * 4 + c) * 512), 16, 0, 0);
      __builtin_amdgcn_global_load_lds((const AS1 void*)(bP[c] + k0),
                                       (AS3 void*)(Bs + (wave * 4 + c) * 512), 16, 0, 0);
    }
    __syncthreads();
#pragma unroll
    for (int kk = 0; kk < BK; kk += 32) {
      const int klo = kk + (lane >> 4) * 8;
      half8 aF[4], bF[4];
#pragma unroll
      for (int m = 0; m < 4; ++m) {
        int r = wr * 64 + m * 16 + (lane & 15);
        aF[m] = *reinterpret_cast<const half8*>(&As[r * BK + swz(r, klo)]);
      }
#pragma unroll
      for (int n = 0; n < 4; ++n) {
        int r = wc * 64 + n * 16 + (lane & 15);
        bF[n] = *reinterpret_cast<const half8*>(&Bs[r * BK + swz(r, klo)]);
      }
#pragma unroll
      for (int m = 0; m < 4; ++m)
#pragma unroll
        for (int n = 0; n < 4; ++n)
          acc[m][n] = __builtin_amdgcn_mfma_f32_16x16x32_f16(aF[m], bF[n], acc[m][n], 0, 0, 0);
    }
    __syncthreads();
  }

#pragma unroll
  for (int m = 0; m < 4; ++m) {
#pragma unroll
    for (int j = 0; j < 4; ++j) {
      int iloc = wr * 64 + m * 16 + (lane >> 4) * 4 + j;
      if (iloc < nrem) {
        int slot = rlist[iloc];
        int t = slot >> 1;
        float wgt = top_w[slot];
#pragma unroll
        for (int n = 0; n < 4; ++n) {
          int c = ct * BN + wc * 64 + n * 16 + (lane & 15);
          float v = acc[m][n][j];
          if (add_bias && ks == 0) v += b2[e * C_DIM + c];
          atomicAdd(out + (size_t)t * C_DIM + c, wgt * v);
        }
      }
    }
  }
}

extern "C" void kernel_launch(void* const* d_in, const int* in_sizes, int n_in,
                              void* d_out, int out_size, void* d_ws, size_t ws_size,
                              hipStream_t stream)
{
  const float* x  = (const float*)d_in[0];
  const float* rw = (const float*)d_in[1];
  const float* w1 = (const float*)d_in[2];
  const float* b1 = (const float*)d_in[3];
  const float* w2 = (const float*)d_in[4];
  const float* b2 = (const float*)d_in[5];
  float* out = (float*)d_out;

  char* ws = (char*)d_ws;
  size_t off = 0;
  auto carve = [&](size_t bytes) -> void* {
    void* p = ws + off;
    off += (bytes + 255) & ~(size_t)255;
    return p;
  };
  int*      top_idx = (int*)carve((size_t)T_TOK * 2 * sizeof(int));
  float*    top_w   = (float*)carve((size_t)T_TOK * 2 * sizeof(float));
  int*      counts  = (int*)carve(E_NUM * sizeof(int));
  int*      rows    = (int*)carve((size_t)E_NUM * T_TOK * sizeof(int));
  _Float16* xh      = (_Float16*)carve((size_t)T_TOK * C_DIM * sizeof(_Float16));
  size_t fixed = off;

  // pick the smallest chunking that fits w1h + w2h + hbuf in workspace
  int nchunk = 8;
  const int cands[4] = {1, 2, 4, 8};
  for (int ci = 0; ci < 4; ++ci) {
    int n = cands[ci];
    size_t fc = (size_t)(F_DIM / n);
    size_t need = fixed
                + (((size_t)E_NUM * fc * C_DIM * 2 + 255) & ~(size_t)255)
                + (((size_t)E_NUM * C_DIM * fc * 2 + 255) & ~(size_t)255)
                + (((size_t)T_TOK * K_TOP * fc * 2 + 255) & ~(size_t)255);
    if (need <= ws_size) { nchunk = n; break; }
  }
  const int Fc = F_DIM / nchunk;
  _Float16* w1h  = (_Float16*)carve((size_t)E_NUM * Fc * C_DIM * sizeof(_Float16));
  _Float16* w2h  = (_Float16*)carve((size_t)E_NUM * C_DIM * Fc * sizeof(_Float16));
  _Float16* hbuf = (_Float16*)carve((size_t)T_TOK * K_TOP * Fc * sizeof(_Float16));

  int kspl = Fc / 1024; if (kspl < 1) kspl = 1;

  hipMemsetAsync(out, 0, (size_t)out_size * sizeof(float), stream);
  router_kernel<<<T_TOK / 4, 256, 0, stream>>>(x, rw, top_idx, top_w, xh);
  build_lists<<<E_NUM, 64, 0, stream>>>(top_idx, rows, counts);

  const int cvt_blocks = (E_NUM * Fc * (C_DIM / 8)) / 256;   // one 8-elem chunk/thread
  for (int ch = 0; ch < nchunk; ++ch) {
    cvt_w1_kernel<<<cvt_blocks, 256, 0, stream>>>(w1, w1h, ch * Fc, Fc);
    cvt_w2_kernel<<<cvt_blocks, 256, 0, stream>>>(w2, w2h, ch * Fc, Fc);
    gemm1_kernel<<<dim3(T_TOK / BM, Fc / BN, E_NUM), 256, 0, stream>>>(
        xh, w1h, b1, rows, counts, hbuf, ch * Fc, Fc);
    gemm2_kernel<<<dim3(T_TOK / BM, 8 * kspl, E_NUM), 256, 0, stream>>>(
        hbuf, w2h, b2, rows, counts, top_w, out, Fc, kspl, ch == 0);
  }
}

// Round 3
// 419.890 us; speedup vs baseline: 2.7658x; 2.7658x over previous
//
#include <hip/hip_runtime.h>
#include <hip/hip_fp16.h>

// MoE B=2,N=2048,C=1024,F=4096,E=8,K=2 (T=4096, slots=8192)
// All GEMM operands pre-packed into contiguous, pre-swizzled 128x64 fp16 tiles
// so every global_load_lds staging step reads a linear 16KB block (DRAM bursts,
// L2/L3 friendly). Gather/scatter handled in the repack passes + epilogues.

#define T_TOK 4096
#define C_DIM 1024
#define F_DIM 4096
#define E_NUM 8
#define BM 128
#define BN 128
#define BK 64
#define MAXT 72            // max global row-tiles: 8192/128 + 7 pad
#define TILE_H 8192        // halfs per 128x64 tile (16KB)

typedef float f32x4 __attribute__((ext_vector_type(4)));
typedef _Float16 half8 __attribute__((ext_vector_type(8)));

#define AS1 __attribute__((address_space(1)))
#define AS3 __attribute__((address_space(3)))

__device__ __forceinline__ int swz(int r, int ec) { return ec ^ ((r & 7) << 3); }

__device__ __forceinline__ half8 cvt8(float4 f0, float4 f1) {
  half8 hv;
  hv[0] = (_Float16)f0.x; hv[1] = (_Float16)f0.y; hv[2] = (_Float16)f0.z; hv[3] = (_Float16)f0.w;
  hv[4] = (_Float16)f1.x; hv[5] = (_Float16)f1.y; hv[6] = (_Float16)f1.z; hv[7] = (_Float16)f1.w;
  return hv;
}

// ---------------- Router: logits -> softmax -> top2 -> normalized weights
__global__ __launch_bounds__(256) void router_kernel(
    const float* __restrict__ x, const float* __restrict__ rw,
    int* __restrict__ top_idx, float* __restrict__ top_w)
{
  int t = blockIdx.x * 4 + (threadIdx.x >> 6);
  int lane = threadIdx.x & 63;
  const float* xr = x + (size_t)t * C_DIM;
  float acc[E_NUM];
#pragma unroll
  for (int e = 0; e < E_NUM; ++e) acc[e] = 0.f;
  for (int j = 0; j < C_DIM / 64; ++j) {
    int c = j * 64 + lane;
    float xv = xr[c];
#pragma unroll
    for (int e = 0; e < E_NUM; ++e) acc[e] += xv * rw[e * C_DIM + c];
  }
#pragma unroll
  for (int e = 0; e < E_NUM; ++e) {
    float v = acc[e];
#pragma unroll
    for (int off = 32; off > 0; off >>= 1) v += __shfl_xor(v, off);
    acc[e] = v;
  }
  if (lane == 0) {
    float mx = acc[0];
    for (int e = 1; e < E_NUM; ++e) mx = fmaxf(mx, acc[e]);
    float p[E_NUM]; float Z = 0.f;
    for (int e = 0; e < E_NUM; ++e) { p[e] = expf(acc[e] - mx); Z += p[e]; }
    int b0 = 0;
    for (int e = 1; e < E_NUM; ++e) if (p[e] > p[b0]) b0 = e;
    int b1i = -1; float pb = -1.f;
    for (int e = 0; e < E_NUM; ++e) if (e != b0 && p[e] > pb) { pb = p[e]; b1i = e; }
    float p0 = p[b0] / Z, p1 = pb / Z;
    float s = p0 + p1 + 1e-9f;
    top_idx[t * 2 + 0] = b0;
    top_idx[t * 2 + 1] = b1i;
    top_w[t * 2 + 0] = p0 / s;
    top_w[t * 2 + 1] = p1 / s;
  }
}

// ---------------- Lists: counts, padded tile offsets, rows_g at global padded positions
__global__ void build_lists(const int* __restrict__ top_idx,
                            int* __restrict__ rows_g, int* __restrict__ counts,
                            int* __restrict__ tile_off)
{
  int e = threadIdx.x >> 6;        // 512 threads = 8 waves, one per expert
  int lane = threadIdx.x & 63;
  int cnt = 0;
  for (int t0 = 0; t0 < T_TOK; t0 += 64) {
    int t = t0 + lane;
    bool sel = (top_idx[t * 2] == e) || (top_idx[t * 2 + 1] == e);
    cnt += __popcll(__ballot(sel));
  }
  if (lane == 0) counts[e] = cnt;
  __syncthreads();
  if (threadIdx.x == 0) {
    int o = 0;
    for (int i = 0; i < E_NUM; ++i) { tile_off[i] = o; o += (counts[i] + BM - 1) / BM; }
    tile_off[E_NUM] = o;
  }
  __syncthreads();
  int base = tile_off[e] * BM;
  int pos = 0;
  for (int t0 = 0; t0 < T_TOK; t0 += 64) {
    int t = t0 + lane;
    int i0 = top_idx[t * 2], i1 = top_idx[t * 2 + 1];
    bool sel = (i0 == e) || (i1 == e);
    unsigned long long mask = __ballot(sel);
    if (sel) {
      int p = pos + __popcll(mask & ((1ull << lane) - 1ull));
      rows_g[base + p] = t * 2 + ((i0 == e) ? 0 : 1);
    }
    pos += __popcll(mask);
  }
}

// ---------------- Gather x -> tiled, pre-swizzled fp16 A for gemm1
__global__ __launch_bounds__(256) void gather_x(
    const float* __restrict__ x, const int* __restrict__ rows_g,
    const int* __restrict__ counts, const int* __restrict__ tile_off,
    _Float16* __restrict__ xg)
{
  unsigned g = blockIdx.x * 256 + threadIdx.x;
  unsigned p = g >> 7, ccr = g & 127;      // position, chunk-in-row
  int gt = p >> 7, r = p & 127;
  int kc = ccr >> 3, c8 = ccr & 7;
  int e = -1;
#pragma unroll
  for (int i = 0; i < E_NUM; ++i)
    if (gt >= tile_off[i] && gt < tile_off[i + 1]) e = i;
  half8 hv = {};
  if (e >= 0) {
    int nrem = counts[e] - (gt - tile_off[e]) * BM;
    if (r < nrem) {
      int t = rows_g[p] >> 1;
      const float4* s = reinterpret_cast<const float4*>(x + (size_t)t * C_DIM + kc * 64 + c8 * 8);
      hv = cvt8(s[0], s[1]);
    }
  }
  *reinterpret_cast<half8*>(xg + ((size_t)gt * 16 + kc) * TILE_H + r * 64 + ((c8 ^ (r & 7)) << 3)) = hv;
}

// ---------------- w1 [E][F][C] fp32 -> tiled fp16 [e][ftl][kc][128][64] (swizzled)
__global__ __launch_bounds__(256) void cvt_w1(
    const float* __restrict__ src, _Float16* __restrict__ dst, int ch, int Fc, int lgFc)
{
  unsigned g = blockIdx.x * 256 + threadIdx.x;
  unsigned row = g >> 7, ccr = g & 127;           // row in [0, 8*Fc)
  int e = row >> lgFc, frow = row & (Fc - 1);
  int ftl = frow >> 7, r = frow & 127;
  int kc = ccr >> 3, c8 = ccr & 7;
  const float4* s = reinterpret_cast<const float4*>(
      src + ((size_t)e * F_DIM + ch * Fc + frow) * C_DIM + kc * 64 + c8 * 8);
  int nft = Fc >> 7;
  size_t tix = ((size_t)(e * nft + ftl) * 16 + kc);
  *reinterpret_cast<half8*>(dst + tix * TILE_H + r * 64 + ((c8 ^ (r & 7)) << 3)) = cvt8(s[0], s[1]);
}

// ---------------- w2 [E][C][F] fp32 -> tiled fp16 [e][ct][kc][128][64] (swizzled)
__global__ __launch_bounds__(256) void cvt_w2(
    const float* __restrict__ src, _Float16* __restrict__ dst, int ch, int Fc, int lgc)
{
  unsigned g = blockIdx.x * 256 + threadIdx.x;
  unsigned row = g >> lgc, ccr = g & ((Fc >> 3) - 1);   // row = e*C + c
  int e = row >> 10, c = row & 1023;
  int ct = c >> 7, r = c & 127;
  int kc = ccr >> 3, c8 = ccr & 7;
  const float4* s = reinterpret_cast<const float4*>(
      src + (size_t)row * F_DIM + ch * Fc + kc * 64 + c8 * 8);
  int nkc = Fc >> 6;
  size_t tix = ((size_t)(e * 8 + ct) * nkc + kc);
  *reinterpret_cast<half8*>(dst + tix * TILE_H + r * 64 + ((c8 ^ (r & 7)) << 3)) = cvt8(s[0], s[1]);
}

// ---------------- GEMM1: ht[pos, f] = relu(xg[pos] . w1t[e][f] + b1)
__global__ __launch_bounds__(256) void gemm1_kernel(
    const _Float16* __restrict__ xg, const _Float16* __restrict__ w1t,
    const float* __restrict__ b1, const int* __restrict__ counts,
    const int* __restrict__ tile_off, _Float16* __restrict__ ht,
    int ch, int Fc)
{
  const int gt = blockIdx.x;
  if (gt >= tile_off[E_NUM]) return;
  int e = 0;
  while (gt >= tile_off[e + 1]) ++e;
  const int nrem = min(counts[e] - (gt - tile_off[e]) * BM, BM);
  const int ft = blockIdx.y;
  const int nft = Fc >> 7;
  const _Float16* At = xg + (size_t)gt * 16 * TILE_H;
  const _Float16* Bt = w1t + (size_t)(e * nft + ft) * 16 * TILE_H;

  __shared__ __align__(16) _Float16 As[TILE_H];
  __shared__ __align__(16) _Float16 Bs[TILE_H];

  const int tid = threadIdx.x;
  const int lane = tid & 63;
  const int wave = tid >> 6;
  const int wr = wave >> 1, wc = wave & 1;

  f32x4 acc[4][4];
#pragma unroll
  for (int m = 0; m < 4; ++m)
#pragma unroll
    for (int n = 0; n < 4; ++n) acc[m][n] = (f32x4){0.f, 0.f, 0.f, 0.f};

  for (int kc = 0; kc < 16; ++kc) {
    const _Float16* a = At + kc * TILE_H + wave * 2048 + lane * 8;
    const _Float16* b = Bt + kc * TILE_H + wave * 2048 + lane * 8;
#pragma unroll
    for (int c = 0; c < 4; ++c) {
      __builtin_amdgcn_global_load_lds((const AS1 void*)(a + c * 512),
                                       (AS3 void*)(As + (wave * 4 + c) * 512), 16, 0, 0);
      __builtin_amdgcn_global_load_lds((const AS1 void*)(b + c * 512),
                                       (AS3 void*)(Bs + (wave * 4 + c) * 512), 16, 0, 0);
    }
    __syncthreads();
#pragma unroll
    for (int kk = 0; kk < BK; kk += 32) {
      const int klo = kk + (lane >> 4) * 8;
      half8 aF[4], bF[4];
#pragma unroll
      for (int m = 0; m < 4; ++m) {
        int r = wr * 64 + m * 16 + (lane & 15);
        aF[m] = *reinterpret_cast<const half8*>(&As[r * BK + swz(r, klo)]);
      }
#pragma unroll
      for (int n = 0; n < 4; ++n) {
        int r = wc * 64 + n * 16 + (lane & 15);
        bF[n] = *reinterpret_cast<const half8*>(&Bs[r * BK + swz(r, klo)]);
      }
#pragma unroll
      for (int m = 0; m < 4; ++m)
#pragma unroll
        for (int n = 0; n < 4; ++n)
          acc[m][n] = __builtin_amdgcn_mfma_f32_16x16x32_f16(aF[m], bF[n], acc[m][n], 0, 0, 0);
    }
    __syncthreads();
  }

  const int nkcF = Fc >> 6;
#pragma unroll
  for (int m = 0; m < 4; ++m) {
#pragma unroll
    for (int j = 0; j < 4; ++j) {
      int iloc = wr * 64 + m * 16 + (lane >> 4) * 4 + j;
      if (iloc < nrem) {
#pragma unroll
        for (int n = 0; n < 4; ++n) {
          int fl = ft * BN + wc * 64 + n * 16 + (lane & 15);
          float v = acc[m][n][j] + b1[e * F_DIM + ch * Fc + fl];
          _Float16 h = (_Float16)fmaxf(v, 0.f);
          ht[((size_t)gt * nkcF + (fl >> 6)) * TILE_H + iloc * 64 +
             ((((fl >> 3) & 7) ^ (iloc & 7)) << 3) + (fl & 7)] = h;
        }
      }
    }
  }
}

// ---------------- GEMM2: out[t] += top_w * (ht[pos] . w2t[e][c] + b2)
__global__ __launch_bounds__(256) void gemm2_kernel(
    const _Float16* __restrict__ ht, const _Float16* __restrict__ w2t,
    const float* __restrict__ b2, const int* __restrict__ rows_g,
    const int* __restrict__ counts, const int* __restrict__ tile_off,
    const float* __restrict__ top_w, float* __restrict__ out,
    int Fc, int kspl, int add_bias)
{
  const int gt = blockIdx.x;
  if (gt >= tile_off[E_NUM]) return;
  int e = 0;
  while (gt >= tile_off[e + 1]) ++e;
  const int nrem = min(counts[e] - (gt - tile_off[e]) * BM, BM);
  const int ct = blockIdx.y & 7;
  const int ks = blockIdx.y >> 3;
  const int nkc = Fc >> 6;
  const int klen = nkc / kspl;
  const _Float16* At = ht + (size_t)gt * nkc * TILE_H;
  const _Float16* Bt = w2t + (size_t)(e * 8 + ct) * nkc * TILE_H;

  __shared__ __align__(16) _Float16 As[TILE_H];
  __shared__ __align__(16) _Float16 Bs[TILE_H];

  const int tid = threadIdx.x;
  const int lane = tid & 63;
  const int wave = tid >> 6;
  const int wr = wave >> 1, wc = wave & 1;

  f32x4 acc[4][4];
#pragma unroll
  for (int m = 0; m < 4; ++m)
#pragma unroll
    for (int n = 0; n < 4; ++n) acc[m][n] = (f32x4){0.f, 0.f, 0.f, 0.f};

  for (int kc = ks * klen; kc < (ks + 1) * klen; ++kc) {
    const _Float16* a = At + (size_t)kc * TILE_H + wave * 2048 + lane * 8;
    const _Float16* b = Bt + (size_t)kc * TILE_H + wave * 2048 + lane * 8;
#pragma unroll
    for (int c = 0; c < 4; ++c) {
      __builtin_amdgcn_global_load_lds((const AS1 void*)(a + c * 512),
                                       (AS3 void*)(As + (wave * 4 + c) * 512), 16, 0, 0);
      __builtin_amdgcn_global_load_lds((const AS1 void*)(b + c * 512),
                                       (AS3 void*)(Bs + (wave * 4 + c) * 512), 16, 0, 0);
    }
    __syncthreads();
#pragma unroll
    for (int kk = 0; kk < BK; kk += 32) {
      const int klo = kk + (lane >> 4) * 8;
      half8 aF[4], bF[4];
#pragma unroll
      for (int m = 0; m < 4; ++m) {
        int r = wr * 64 + m * 16 + (lane & 15);
        aF[m] = *reinterpret_cast<const half8*>(&As[r * BK + swz(r, klo)]);
      }
#pragma unroll
      for (int n = 0; n < 4; ++n) {
        int r = wc * 64 + n * 16 + (lane & 15);
        bF[n] = *reinterpret_cast<const half8*>(&Bs[r * BK + swz(r, klo)]);
      }
#pragma unroll
      for (int m = 0; m < 4; ++m)
#pragma unroll
        for (int n = 0; n < 4; ++n)
          acc[m][n] = __builtin_amdgcn_mfma_f32_16x16x32_f16(aF[m], bF[n], acc[m][n], 0, 0, 0);
    }
    __syncthreads();
  }

#pragma unroll
  for (int m = 0; m < 4; ++m) {
#pragma unroll
    for (int j = 0; j < 4; ++j) {
      int iloc = wr * 64 + m * 16 + (lane >> 4) * 4 + j;
      if (iloc < nrem) {
        int slot = rows_g[gt * BM + iloc];
        int t = slot >> 1;
        float wgt = top_w[slot];
#pragma unroll
        for (int n = 0; n < 4; ++n) {
          int c = ct * BN + wc * 64 + n * 16 + (lane & 15);
          float v = acc[m][n][j];
          if (add_bias && ks == 0) v += b2[e * C_DIM + c];
          atomicAdd(out + (size_t)t * C_DIM + c, wgt * v);
        }
      }
    }
  }
}

extern "C" void kernel_launch(void* const* d_in, const int* in_sizes, int n_in,
                              void* d_out, int out_size, void* d_ws, size_t ws_size,
                              hipStream_t stream)
{
  const float* x  = (const float*)d_in[0];
  const float* rw = (const float*)d_in[1];
  const float* w1 = (const float*)d_in[2];
  const float* b1 = (const float*)d_in[3];
  const float* w2 = (const float*)d_in[4];
  const float* b2 = (const float*)d_in[5];
  float* out = (float*)d_out;

  char* ws = (char*)d_ws;
  size_t off = 0;
  auto carve = [&](size_t bytes) -> void* {
    void* p = ws + off;
    off += (bytes + 255) & ~(size_t)255;
    return p;
  };
  int*   top_idx  = (int*)carve((size_t)T_TOK * 2 * sizeof(int));
  float* top_w    = (float*)carve((size_t)T_TOK * 2 * sizeof(float));
  int*   counts   = (int*)carve(E_NUM * sizeof(int));
  int*   tile_off = (int*)carve((E_NUM + 1) * sizeof(int));
  int*   rows_g   = (int*)carve((size_t)MAXT * BM * sizeof(int));
  _Float16* xg    = (_Float16*)carve((size_t)MAXT * 16 * TILE_H * sizeof(_Float16));
  size_t fixed = off;

  // pick smallest F-chunking that fits w1t + w2t + ht
  int nchunk = 8;
  const int cands[4] = {1, 2, 4, 8};
  for (int ci = 0; ci < 4; ++ci) {
    int n = cands[ci];
    size_t fc = (size_t)(F_DIM / n);
    size_t w1b = ((size_t)E_NUM * fc * C_DIM * 2 + 255) & ~(size_t)255;
    size_t w2b = ((size_t)E_NUM * C_DIM * fc * 2 + 255) & ~(size_t)255;
    size_t htb = ((size_t)MAXT * (fc >> 6) * TILE_H * 2 + 255) & ~(size_t)255;
    if (fixed + w1b + w2b + htb <= ws_size) { nchunk = n; break; }
  }
  const int Fc = F_DIM / nchunk;
  int lgFc = 0; while ((1 << lgFc) < Fc) ++lgFc;
  _Float16* w1t = (_Float16*)carve((size_t)E_NUM * Fc * C_DIM * sizeof(_Float16));
  _Float16* w2t = (_Float16*)carve((size_t)E_NUM * C_DIM * Fc * sizeof(_Float16));
  _Float16* ht  = (_Float16*)carve((size_t)MAXT * (Fc >> 6) * TILE_H * sizeof(_Float16));

  const int kspl = (Fc >= 2048) ? 2 : 1;

  hipMemsetAsync(out, 0, (size_t)out_size * sizeof(float), stream);
  router_kernel<<<T_TOK / 4, 256, 0, stream>>>(x, rw, top_idx, top_w);
  build_lists<<<1, 512, 0, stream>>>(top_idx, rows_g, counts, tile_off);
  gather_x<<<(MAXT * BM * 128) / 256, 256, 0, stream>>>(x, rows_g, counts, tile_off, xg);

  const int cvt_blocks = 4 * Fc;   // 8*Fc rows * (width/8) chunks / 256, for both layouts
  for (int ch = 0; ch < nchunk; ++ch) {
    cvt_w1<<<cvt_blocks, 256, 0, stream>>>(w1, w1t, ch, Fc, lgFc);
    cvt_w2<<<cvt_blocks, 256, 0, stream>>>(w2, w2t, ch, Fc, lgFc - 3);
    gemm1_kernel<<<dim3(MAXT, Fc / BN), 256, 0, stream>>>(
        xg, w1t, b1, counts, tile_off, ht, ch, Fc);
    gemm2_kernel<<<dim3(MAXT, 8 * kspl), 256, 0, stream>>>(
        ht, w2t, b2, rows_g, counts, tile_off, top_w, out, Fc, kspl, ch == 0);
  }
}